// Round 1
// baseline (6823.587 us; speedup 1.0000x reference)
//
#include <hip/hip_runtime.h>
#include <stdint.h>

// Problem constants
#define LL 6
#define DM 1024
#define NH 16
#define DH 64
#define DF_ 4096
#define VV 32000
#define SS 512
#define MM 1024
#define BB 8

typedef unsigned short u16;
typedef float f32x4 __attribute__((ext_vector_type(4)));
typedef __bf16 bf16x8 __attribute__((ext_vector_type(8)));

__device__ __forceinline__ u16 f2bf(float f) {
  uint32_t u = __float_as_uint(f);
  u += 0x7fffu + ((u >> 16) & 1u);
  return (u16)(u >> 16);
}
__device__ __forceinline__ void store_bf16x4(u16* dst, f32x4 v) {
  uint32_t lo = (uint32_t)f2bf(v.x) | ((uint32_t)f2bf(v.y) << 16);
  uint32_t hi = (uint32_t)f2bf(v.z) | ((uint32_t)f2bf(v.w) << 16);
  uint2 u; u.x = lo; u.y = hi;
  *(uint2*)dst = u;
}
__device__ __forceinline__ void async_copy16(const void* g, void* l) {
  __builtin_amdgcn_global_load_lds((__attribute__((address_space(1))) void*)g,
                                   (__attribute__((address_space(3))) void*)l, 16, 0, 0);
}

// ---------------- embedding: x = input_embed[seq] + pos_embed ----------------
__global__ void embed_kernel(const int* __restrict__ seq, const float* __restrict__ emb,
                             const float* __restrict__ pos, float* __restrict__ xf,
                             u16* __restrict__ xb) {
  int row = blockIdx.x;               // B*S rows
  int c4 = threadIdx.x * 4;           // 256 threads * 4 = 1024
  int tok = seq[row];
  int s = row & (SS - 1);
  f32x4 e = *(const f32x4*)(emb + (size_t)tok * DM + c4);
  f32x4 p = *(const f32x4*)(pos + (size_t)s * DM + c4);
  f32x4 v = e + p;
  *(f32x4*)(xf + (size_t)row * DM + c4) = v;
  store_bf16x4(xb + (size_t)row * DM + c4, v);
}

// ---------------- plain fp32 -> bf16 convert ----------------
__global__ void conv_bf16(const float* __restrict__ in, u16* __restrict__ out, long n) {
  long i = ((long)blockIdx.x * 256 + threadIdx.x) * 4;
  if (i + 3 >= n + 4) return;
  f32x4 v = *(const f32x4*)(in + i);
  store_bf16x4(out + i, v);
}

// ---------------- tiled transpose + convert fp32[R,C] -> bf16[C,R] ----------------
__global__ void transpose_conv(const float* __restrict__ in, u16* __restrict__ out,
                               int H, long in_hi, long in_lo, int in_ld,
                               long out_hi, long out_lo, int out_ld) {
  __shared__ float tile[32][33];
  int z = blockIdx.z;
  long ib = (long)(z / H) * in_hi + (long)(z % H) * in_lo;
  long ob = (long)(z / H) * out_hi + (long)(z % H) * out_lo;
  int c0 = blockIdx.x * 32, r0 = blockIdx.y * 32;
  int tx = threadIdx.x, ty = threadIdx.y; // (32,8)
#pragma unroll
  for (int i = 0; i < 4; i++)
    tile[ty + i * 8][tx] = in[ib + (long)(r0 + ty + i * 8) * in_ld + c0 + tx];
  __syncthreads();
#pragma unroll
  for (int i = 0; i < 4; i++)
    out[ob + (long)(c0 + ty + i * 8) * out_ld + r0 + tx] = f2bf(tile[tx][ty + i * 8]);
}

// ---------------- residual + LayerNorm (fp32 in/out + bf16 mirror) ----------------
__global__ void ln_kernel(const float* __restrict__ x, const float* __restrict__ r,
                          const float* __restrict__ s, const float* __restrict__ b,
                          float* __restrict__ xo, u16* __restrict__ xbo) {
  int row = blockIdx.x;
  int t = threadIdx.x; // 256
  const float* xp = x + (size_t)row * DM;
  float v[4];
  float sum = 0.f, sq = 0.f;
#pragma unroll
  for (int i = 0; i < 4; i++) {
    float a = xp[t + i * 256];
    if (r) a += r[(size_t)row * DM + t + i * 256];
    v[i] = a; sum += a; sq += a * a;
  }
  __shared__ float rs[4], rq[4], mv[2];
  int wv = t >> 6, ln = t & 63;
#pragma unroll
  for (int off = 32; off; off >>= 1) {
    sum += __shfl_xor(sum, off);
    sq  += __shfl_xor(sq, off);
  }
  if (ln == 0) { rs[wv] = sum; rq[wv] = sq; }
  __syncthreads();
  if (t == 0) {
    float ts = rs[0] + rs[1] + rs[2] + rs[3];
    float tq = rq[0] + rq[1] + rq[2] + rq[3];
    float mu = ts / DM;
    float var = tq / DM - mu * mu;
    mv[0] = mu; mv[1] = rsqrtf(var + 1e-5f);
  }
  __syncthreads();
  float mu = mv[0], rstd = mv[1];
#pragma unroll
  for (int i = 0; i < 4; i++) {
    int d = t + i * 256;
    float o = (v[i] - mu) * rstd * s[d] + b[d];
    if (xo) xo[(size_t)row * DM + d] = o;
    xbo[(size_t)row * DM + d] = f2bf(o);
  }
}

// ---------------- softmax over score rows (scale 1/8, optional causal) ----------------
__global__ void softmax_kernel(const float* __restrict__ sc, u16* __restrict__ P,
                               int Skv, int causal) {
  int row = blockIdx.x * 4 + (threadIdx.x >> 6); // z*S + q
  int ln = threadIdx.x & 63;
  int q = row & (SS - 1);
  const float* sp = sc + (size_t)row * Skv;
  int len = causal ? (q + 1) : Skv;
  float mx = -1e30f;
  for (int i = ln; i < len; i += 64) mx = fmaxf(mx, sp[i] * 0.125f);
#pragma unroll
  for (int off = 32; off; off >>= 1) mx = fmaxf(mx, __shfl_xor(mx, off));
  float sm = 0.f;
  for (int i = ln; i < len; i += 64) sm += __expf(sp[i] * 0.125f - mx);
#pragma unroll
  for (int off = 32; off; off >>= 1) sm += __shfl_xor(sm, off);
  float inv = 1.f / sm;
  u16* pp = P + (size_t)row * Skv;
  for (int i = ln; i < Skv; i += 64)
    pp[i] = (i < len) ? f2bf(__expf(sp[i] * 0.125f - mx) * inv) : (u16)0;
}

// ---------------- NT bf16 MFMA GEMM: C[m,n] = sum_k A[m,k]*B[n,k] ----------------
// MODE 0: fp32 store    MODE 1: fp32 + bias[n]    MODE 2: bf16(relu(acc+bias[n]))
// MODE 3: bf16 per-head permuted store (q/k proj) MODE 4: bf16 store (batched addr)
template <int BM, int BN, int MODE>
__launch_bounds__(256)
__global__ void gemm_nt(const u16* __restrict__ A, const u16* __restrict__ Bm,
                        void* __restrict__ C, const float* __restrict__ bias,
                        int M_, int N_, int K, int lda, int ldb, int ldc,
                        long batchA, long batchB, int CH, long c_hi, long c_lo,
                        int permShift) {
  constexpr int WGM = 2, WGN = 2;
  constexpr int WM = BM / WGM, WN = BN / WGN;
  constexpr int FM = WM / 16, FN = WN / 16;
  __shared__ __align__(16) u16 As[BM * 32];
  __shared__ __align__(16) u16 Bs[BN * 32];
  int z = blockIdx.z;
  const u16* Ab = A + (size_t)z * batchA;
  const u16* Bb = Bm + (size_t)z * batchB;
  int tile_m = blockIdx.y * BM;
  int tile_n = blockIdx.x * BN;
  int t = threadIdx.x;
  int wv = t >> 6, ln = t & 63;
  int wm = wv / WGN, wn = wv % WGN;

  f32x4 acc[FM][FN];
#pragma unroll
  for (int i = 0; i < FM; i++)
#pragma unroll
    for (int j = 0; j < FN; j++) acc[i][j] = (f32x4){0.f, 0.f, 0.f, 0.f};

  int fr_m = ln & 15;
  int fr_k = (ln >> 4) * 8;

  for (int k0 = 0; k0 < K; k0 += 32) {
#pragma unroll
    for (int ss = 0; ss < (BM * 4) / 256; ss++) {
      int seg = t + ss * 256;
      int row = seg >> 2, cs = (seg & 3) * 8;
      async_copy16(Ab + (size_t)(tile_m + row) * lda + k0 + cs, (char*)As + seg * 16);
    }
#pragma unroll
    for (int ss = 0; ss < (BN * 4) / 256; ss++) {
      int seg = t + ss * 256;
      int row = seg >> 2, cs = (seg & 3) * 8;
      async_copy16(Bb + (size_t)(tile_n + row) * ldb + k0 + cs, (char*)Bs + seg * 16);
    }
    __syncthreads();
    bf16x8 af[FM], bfr[FN];
#pragma unroll
    for (int i = 0; i < FM; i++)
      af[i] = *(const bf16x8*)&As[(wm * WM + i * 16 + fr_m) * 32 + fr_k];
#pragma unroll
    for (int j = 0; j < FN; j++)
      bfr[j] = *(const bf16x8*)&Bs[(wn * WN + j * 16 + fr_m) * 32 + fr_k];
#pragma unroll
    for (int i = 0; i < FM; i++)
#pragma unroll
      for (int j = 0; j < FN; j++)
        acc[i][j] = __builtin_amdgcn_mfma_f32_16x16x32_bf16(af[i], bfr[j], acc[i][j], 0, 0, 0);
    __syncthreads();
  }

  long cbase = (long)(z / CH) * c_hi + (long)(z % CH) * c_lo;
  int col0 = tile_n + wn * WN;
  int row0 = tile_m + wm * WM;
  int cfr = ln & 15;
  int rfr = (ln >> 4) * 4;
#pragma unroll
  for (int i = 0; i < FM; i++) {
#pragma unroll
    for (int j = 0; j < FN; j++) {
      int n = col0 + j * 16 + cfr;
#pragma unroll
      for (int rr = 0; rr < 4; rr++) {
        int m = row0 + i * 16 + rfr + rr;
        float v = acc[i][j][rr];
        if (MODE == 0) {
          ((float*)C)[cbase + (long)m * ldc + n] = v;
        } else if (MODE == 1) {
          ((float*)C)[cbase + (long)m * ldc + n] = v + bias[n];
        } else if (MODE == 2) {
          float o = v + bias[n];
          o = o > 0.f ? o : 0.f;
          ((u16*)C)[cbase + (long)m * ldc + n] = f2bf(o);
        } else if (MODE == 3) {
          int bb = m >> permShift;
          int s = m & ((1 << permShift) - 1);
          int h = n >> 6, d = n & 63;
          long idx = (((long)(bb * 16 + h)) << permShift) * 64 + (long)s * 64 + d;
          ((u16*)C)[idx] = f2bf(v);
        } else {
          ((u16*)C)[cbase + (long)m * ldc + n] = f2bf(v);
        }
      }
    }
  }
}

extern "C" void kernel_launch(void* const* d_in, const int* in_sizes, int n_in,
                              void* d_out, int out_size, void* d_ws, size_t ws_size,
                              hipStream_t stream) {
  const float* encoded      = (const float*)d_in[0];
  const int*   seq          = (const int*)d_in[1];
  const float* input_embed  = (const float*)d_in[2];
  const float* output_embed = (const float*)d_in[3];
  const float* output_bias  = (const float*)d_in[4];
  const float* pos_embed    = (const float*)d_in[5];
  const float* Wlist[8] = { (const float*)d_in[6], (const float*)d_in[7],
                            (const float*)d_in[8], (const float*)d_in[9],
                            (const float*)d_in[10], (const float*)d_in[11],
                            (const float*)d_in[12], (const float*)d_in[13] };
  const float* W1  = (const float*)d_in[14];
  const float* b1  = (const float*)d_in[15];
  const float* W2  = (const float*)d_in[16];
  const float* b2  = (const float*)d_in[17];
  const float* ln1s = (const float*)d_in[18];
  const float* ln1b = (const float*)d_in[19];
  const float* ln2s = (const float*)d_in[20];
  const float* ln2b = (const float*)d_in[21];
  const float* ln3s = (const float*)d_in[22];
  const float* ln3b = (const float*)d_in[23];
  const float* lnfs = (const float*)d_in[24];
  const float* lnfb = (const float*)d_in[25];

  char* ws = (char*)d_ws;
  size_t off = 0;
  auto alloc = [&](size_t n) { char* p = ws + off; off += (n + 255) & ~(size_t)255; return (void*)p; };

  u16* WT[8];
  for (int i = 0; i < 8; i++) WT[i] = (u16*)alloc((size_t)LL * DM * DM * 2);
  u16* W1T   = (u16*)alloc((size_t)LL * DF_ * DM * 2);
  u16* W2T   = (u16*)alloc((size_t)LL * DM * DF_ * 2);
  u16* oembT = (u16*)alloc((size_t)VV * DM * 2);
  u16* encb  = (u16*)alloc((size_t)BB * MM * DM * 2);
  float* xf  = (float*)alloc((size_t)BB * SS * DM * 4);
  u16* xb    = (u16*)alloc((size_t)BB * SS * DM * 2);
  u16* qp    = (u16*)alloc((size_t)BB * SS * DM * 2);
  u16* kp    = (u16*)alloc((size_t)BB * MM * DM * 2);
  float* vf  = (float*)alloc((size_t)BB * MM * DM * 4);
  u16* vt    = (u16*)alloc((size_t)BB * MM * DM * 2);
  float* sc  = (float*)alloc((size_t)BB * NH * SS * MM * 4);
  u16* Pb    = (u16*)alloc((size_t)BB * NH * SS * MM * 2);
  u16* ob    = (u16*)alloc((size_t)BB * SS * DM * 2);
  float* attn = (float*)alloc((size_t)BB * SS * DM * 4);
  u16* hb    = (u16*)alloc((size_t)BB * SS * DF_ * 2);
  float* ffn = (float*)alloc((size_t)BB * SS * DM * 4);
  (void)ws_size; (void)in_sizes; (void)n_in; (void)out_size;

  // ---- weight conversion (every launch; inputs restored each call) ----
  for (int i = 0; i < 8; i++)
    transpose_conv<<<dim3(32, 32, LL), dim3(32, 8), 0, stream>>>(
        Wlist[i], WT[i], 1, 1048576, 0, 1024, 1048576, 0, 1024);
  transpose_conv<<<dim3(128, 32, LL), dim3(32, 8), 0, stream>>>(
      W1, W1T, 1, 4194304, 0, 4096, 4194304, 0, 1024);
  transpose_conv<<<dim3(32, 128, LL), dim3(32, 8), 0, stream>>>(
      W2, W2T, 1, 4194304, 0, 1024, 4194304, 0, 4096);
  conv_bf16<<<32000, 256, 0, stream>>>(output_embed, oembT, (long)VV * DM);
  conv_bf16<<<8192, 256, 0, stream>>>(encoded, encb, (long)BB * MM * DM);
  embed_kernel<<<BB * SS, 256, 0, stream>>>(seq, input_embed, pos_embed, xf, xb);

  const int Mx = BB * SS;   // 4096
  const int Me = BB * MM;   // 8192

  for (int l = 0; l < LL; l++) {
    const u16* WqTl  = WT[0] + (size_t)l * DM * DM;
    const u16* WkTl  = WT[1] + (size_t)l * DM * DM;
    const u16* WvTl  = WT[2] + (size_t)l * DM * DM;
    const u16* WoTl  = WT[3] + (size_t)l * DM * DM;
    const u16* WqcTl = WT[4] + (size_t)l * DM * DM;
    const u16* WkcTl = WT[5] + (size_t)l * DM * DM;
    const u16* WvcTl = WT[6] + (size_t)l * DM * DM;
    const u16* WocTl = WT[7] + (size_t)l * DM * DM;

    // ---------------- self attention ----------------
    gemm_nt<128,128,3><<<dim3(8,32,1),256,0,stream>>>(xb, WqTl, qp, nullptr,
        Mx,1024,1024, 1024,1024,0, 0,0, 1,0,0, 9);
    gemm_nt<128,128,3><<<dim3(8,32,1),256,0,stream>>>(xb, WkTl, kp, nullptr,
        Mx,1024,1024, 1024,1024,0, 0,0, 1,0,0, 9);
    gemm_nt<128,128,0><<<dim3(8,32,1),256,0,stream>>>(xb, WvTl, vf, nullptr,
        Mx,1024,1024, 1024,1024,1024, 0,0, 1,0,0, 0);
    transpose_conv<<<dim3(2,16,128), dim3(32,8), 0, stream>>>(
        vf, vt, 16, 524288, 64, 1024, 524288, 32768, 512);
    gemm_nt<128,128,0><<<dim3(4,4,128),256,0,stream>>>(qp, kp, sc, nullptr,
        512,512,64, 64,64,512, 32768,32768, 1,262144,0, 0);
    softmax_kernel<<<16384,256,0,stream>>>(sc, Pb, 512, 1);
    gemm_nt<64,64,4><<<dim3(1,8,128),256,0,stream>>>(Pb, vt, ob, nullptr,
        512,64,512, 512,512,1024, 262144,32768, 16,524288,64, 0);
    gemm_nt<128,128,0><<<dim3(8,32,1),256,0,stream>>>(ob, WoTl, attn, nullptr,
        Mx,1024,1024, 1024,1024,1024, 0,0, 1,0,0, 0);
    ln_kernel<<<Mx,256,0,stream>>>(xf, attn, ln1s + l*DM, ln1b + l*DM, xf, xb);

    // ---------------- cross attention ----------------
    gemm_nt<128,128,3><<<dim3(8,32,1),256,0,stream>>>(xb, WqcTl, qp, nullptr,
        Mx,1024,1024, 1024,1024,0, 0,0, 1,0,0, 9);
    gemm_nt<128,128,3><<<dim3(8,64,1),256,0,stream>>>(encb, WkcTl, kp, nullptr,
        Me,1024,1024, 1024,1024,0, 0,0, 1,0,0, 10);
    gemm_nt<128,128,0><<<dim3(8,64,1),256,0,stream>>>(encb, WvcTl, vf, nullptr,
        Me,1024,1024, 1024,1024,1024, 0,0, 1,0,0, 0);
    transpose_conv<<<dim3(2,32,128), dim3(32,8), 0, stream>>>(
        vf, vt, 16, 1048576, 64, 1024, 1048576, 65536, 1024);
    gemm_nt<128,128,0><<<dim3(8,4,128),256,0,stream>>>(qp, kp, sc, nullptr,
        512,1024,64, 64,64,1024, 32768,65536, 1,524288,0, 0);
    softmax_kernel<<<16384,256,0,stream>>>(sc, Pb, 1024, 0);
    gemm_nt<64,64,4><<<dim3(1,8,128),256,0,stream>>>(Pb, vt, ob, nullptr,
        512,64,1024, 1024,1024,1024, 524288,65536, 16,524288,64, 0);
    gemm_nt<128,128,0><<<dim3(8,32,1),256,0,stream>>>(ob, WocTl, attn, nullptr,
        Mx,1024,1024, 1024,1024,1024, 0,0, 1,0,0, 0);
    ln_kernel<<<Mx,256,0,stream>>>(xf, attn, ln2s + l*DM, ln2b + l*DM, xf, xb);

    // ---------------- FFN ----------------
    gemm_nt<128,128,2><<<dim3(32,32,1),256,0,stream>>>(xb, W1T + (size_t)l*DF_*DM, hb,
        b1 + (size_t)l*DF_, Mx,4096,1024, 1024,1024,4096, 0,0, 1,0,0, 0);
    gemm_nt<128,128,1><<<dim3(8,32,1),256,0,stream>>>(hb, W2T + (size_t)l*DM*DF_, ffn,
        b2 + (size_t)l*DM, Mx,1024,4096, 4096,4096,1024, 0,0, 1,0,0, 0);
    ln_kernel<<<Mx,256,0,stream>>>(xf, ffn, ln3s + l*DM, ln3b + l*DM, xf, xb);
  }

  // final norm + vocab projection
  ln_kernel<<<Mx,256,0,stream>>>(xf, nullptr, lnfs, lnfb, xf, xb);
  gemm_nt<128,128,1><<<dim3(250,32,1),256,0,stream>>>(xb, oembT, (float*)d_out,
      output_bias, Mx,32000,1024, 1024,1024,32000, 0,0, 1,0,0, 0);
}